// Round 11
// baseline (2567.714 us; speedup 1.0000x reference)
//
#include <hip/hip_runtime.h>
#include <stdint.h>

#define NN 50000
#define EE 400000

typedef unsigned short u16;
typedef __attribute__((ext_vector_type(8))) short bf16x8;
typedef __attribute__((ext_vector_type(4))) float f32x4;
typedef __attribute__((address_space(3))) uint32_t lds_u32_t;
typedef __attribute__((address_space(1))) uint32_t glob_u32_t;

__device__ inline float bf2f(u16 u) {
  union { uint32_t i; float f; } x; x.i = ((uint32_t)u) << 16; return x.f;
}
__device__ inline u16 f2bf(float f) {
  union { float f; uint32_t i; } x; x.f = f;
  x.i += 0x7fffu + ((x.i >> 16) & 1u);   // RNE
  return (u16)(x.i >> 16);
}
__device__ inline void gload_lds16(const void* g, void* l) {
  __builtin_amdgcn_global_load_lds((const glob_u32_t*)g, (lds_u32_t*)l, 16, 0, 0);
}

// ---------------- edge dtype detect + normalize ----------------
__global__ void detect_i64(const int* __restrict__ e, int* __restrict__ flag) {
  __shared__ int sh[256];
  int t = threadIdx.x;
  int v = 0;
  for (int i = t; i < 4096; i += 256) v |= e[2 * i + 1];
  sh[t] = v; __syncthreads();
  for (int s = 128; s > 0; s >>= 1) { if (t < s) sh[t] |= sh[t + s]; __syncthreads(); }
  if (t == 0) flag[0] = (sh[0] == 0) ? 1 : 0;   // all high words zero -> int64
}

__global__ void conv_edges(const int* __restrict__ e, const int* __restrict__ flag,
                           int* __restrict__ src, int* __restrict__ dst) {
  int i = blockIdx.x * 256 + threadIdx.x;
  if (i >= EE) return;
  if (flag[0]) { src[i] = e[2 * i]; dst[i] = e[2 * (EE + i)]; }
  else         { src[i] = e[i];     dst[i] = e[EE + i]; }
}

// ---------------- CSR build ----------------
__global__ void count_edges(const int* __restrict__ dst, int* __restrict__ cnt) {
  int i = blockIdx.x * 256 + threadIdx.x;
  if (i < EE) atomicAdd(&cnt[dst[i]], 1);
}

__global__ void scan_counts(const int* __restrict__ cnt, int* __restrict__ offs,
                            int* __restrict__ cursor) {
  __shared__ int sh[1024];
  __shared__ int carry_sh;
  int tid = threadIdx.x;
  if (tid == 0) carry_sh = 0;
  __syncthreads();
  int nChunks = (NN + 1023) / 1024;
  for (int c = 0; c < nChunks; ++c) {
    int idx = c * 1024 + tid;
    int v = (idx < NN) ? cnt[idx] : 0;
    sh[tid] = v; __syncthreads();
    for (int off = 1; off < 1024; off <<= 1) {
      int t = (tid >= off) ? sh[tid - off] : 0;
      __syncthreads();
      sh[tid] += t;
      __syncthreads();
    }
    int incl = sh[tid];
    int excl = incl - v + carry_sh;
    if (idx < NN) { offs[idx] = excl; cursor[idx] = excl; }
    __syncthreads();
    if (tid == 0) carry_sh += sh[1023];
    __syncthreads();
  }
}

__global__ void fill_buckets(const int* __restrict__ src, const int* __restrict__ dst,
                             int* __restrict__ cursor, int* __restrict__ bucket) {
  int i = blockIdx.x * 256 + threadIdx.x;
  if (i >= EE) return;
  int p = atomicAdd(&cursor[dst[i]], 1);
  bucket[p] = src[i];
}

// ---------------- fp32 -> bf16 conversions ----------------
__global__ void cvt_bf16(const float* __restrict__ in, u16* __restrict__ out, int n4) {
  int i = blockIdx.x * 256 + threadIdx.x;
  if (i >= n4) return;
  float4 v = ((const float4*)in)[i];
  u16 o[4] = { f2bf(v.x), f2bf(v.y), f2bf(v.z), f2bf(v.w) };
  uint2 pack;
  pack.x = (uint32_t)o[0] | ((uint32_t)o[1] << 16);
  pack.y = (uint32_t)o[2] | ((uint32_t)o[3] << 16);
  ((uint2*)out)[i] = pack;
}

// W [K][Nc] fp32 -> Wt [Nc][K] bf16
__global__ void transposeW(const float* __restrict__ W, u16* __restrict__ Wt,
                           int K, int Nc) {
  __shared__ float tile[32][33];
  int n0 = blockIdx.x * 32, k0 = blockIdx.y * 32;
  int tx = threadIdx.x, ty = threadIdx.y;  // 32 x 8
  #pragma unroll
  for (int i = 0; i < 4; ++i)
    tile[ty + i * 8][tx] = W[(size_t)(k0 + ty + i * 8) * Nc + n0 + tx];
  __syncthreads();
  #pragma unroll
  for (int i = 0; i < 4; ++i)
    Wt[(size_t)(n0 + ty + i * 8) * K + k0 + tx] = f2bf(tile[tx][ty + i * 8]);
}

// ---------------- mean aggregation (CSR gather) ----------------
template<int D>
__global__ void agg_mean(const u16* __restrict__ h, const int* __restrict__ offs,
                         const int* __restrict__ cnt, const int* __restrict__ bucket,
                         u16* __restrict__ outp) {
  int node = blockIdx.x;
  int t = threadIdx.x;
  int base = t * 8;
  if (base >= D) return;
  int start = offs[node];
  int c = cnt[node];
  float acc[8];
  #pragma unroll
  for (int i = 0; i < 8; ++i) acc[i] = 0.f;
  for (int j = 0; j < c; ++j) {
    int s = bucket[start + j];
    uint4 q = *(const uint4*)(h + (size_t)s * D + base);
    acc[0] += bf2f((u16)(q.x & 0xffff)); acc[1] += bf2f((u16)(q.x >> 16));
    acc[2] += bf2f((u16)(q.y & 0xffff)); acc[3] += bf2f((u16)(q.y >> 16));
    acc[4] += bf2f((u16)(q.z & 0xffff)); acc[5] += bf2f((u16)(q.z >> 16));
    acc[6] += bf2f((u16)(q.w & 0xffff)); acc[7] += bf2f((u16)(q.w >> 16));
  }
  float inv = 1.0f / fmaxf((float)c, 1.0f);
  uint4 o;
  o.x = (uint32_t)f2bf(acc[0] * inv) | ((uint32_t)f2bf(acc[1] * inv) << 16);
  o.y = (uint32_t)f2bf(acc[2] * inv) | ((uint32_t)f2bf(acc[3] * inv) << 16);
  o.z = (uint32_t)f2bf(acc[4] * inv) | ((uint32_t)f2bf(acc[5] * inv) << 16);
  o.w = (uint32_t)f2bf(acc[6] * inv) | ((uint32_t)f2bf(acc[7] * inv) << 16);
  *(uint4*)(outp + (size_t)node * D + base) = o;
}

// ---- fused layer-3 tail: out = l2norm(relu(mean(Y_l[nbrs]) + Y_r + b3)) ----
__global__ void agg_add_norm(const u16* __restrict__ Y, const int* __restrict__ offs,
                             const int* __restrict__ cnt, const int* __restrict__ bucket,
                             const float* __restrict__ b3, float* __restrict__ outp) {
  int node = blockIdx.x;
  int t = threadIdx.x;
  int base = t * 4;  // 0..1023
  int start = offs[node];
  int c = cnt[node];
  float acc[4] = {0.f, 0.f, 0.f, 0.f};
  for (int j = 0; j < c; ++j) {
    int s = bucket[start + j];
    uint2 q = *(const uint2*)(Y + (size_t)s * 2048 + base);
    acc[0] += bf2f((u16)(q.x & 0xffff)); acc[1] += bf2f((u16)(q.x >> 16));
    acc[2] += bf2f((u16)(q.y & 0xffff)); acc[3] += bf2f((u16)(q.y >> 16));
  }
  float inv = 1.0f / fmaxf((float)c, 1.0f);
  uint2 qr = *(const uint2*)(Y + (size_t)node * 2048 + 1024 + base);
  float yr[4] = { bf2f((u16)(qr.x & 0xffff)), bf2f((u16)(qr.x >> 16)),
                  bf2f((u16)(qr.y & 0xffff)), bf2f((u16)(qr.y >> 16)) };
  float4 bv = *(const float4*)(b3 + base);
  float v[4];
  v[0] = fmaxf(acc[0] * inv + yr[0] + bv.x, 0.f);
  v[1] = fmaxf(acc[1] * inv + yr[1] + bv.y, 0.f);
  v[2] = fmaxf(acc[2] * inv + yr[2] + bv.z, 0.f);
  v[3] = fmaxf(acc[3] * inv + yr[3] + bv.w, 0.f);
  float ss = v[0] * v[0] + v[1] * v[1] + v[2] * v[2] + v[3] * v[3];
  #pragma unroll
  for (int off = 32; off > 0; off >>= 1) ss += __shfl_down(ss, off);
  __shared__ float sw[4];
  int lane = t & 63, w = t >> 6;
  if (lane == 0) sw[w] = ss;
  __syncthreads();
  float total = sw[0] + sw[1] + sw[2] + sw[3];
  float scale = 1.0f / fmaxf(sqrtf(total), 1e-12f);
  float4 o = { v[0] * scale, v[1] * scale, v[2] * scale, v[3] * scale };
  *(float4*)(outp + (size_t)node * 1024 + base) = o;
}

// ---------------- 256x256 GEMM: A via LDS, B direct global->VGPR ------------
// C[M,Nc] = [relu](A1@B1t' [+ A2@B2t'] [+ bias]), A bf16 [M,K], Bt bf16 [Nc][K]
// Tile 256x256, BK=64, 8 waves (2M x 4N).
// R11 THESIS: 6 schedule variants all measured ~5400 cyc/K-tile = MFMA(2483)
// + LDS pipe(~2300) serialized -> cut LDS bytes instead of reordering.
// B fragments are loaded global->VGPR directly (lane's frag = 16 contiguous
// bytes of Bt at row colBase+NH*128+wn*32+nf*16+(lane&15), k0+ks*32+kg*8 --
// identical algebra to the old LDS read). B prefetched ONE K-TILE AHEAD into
// a second register set (2-tile unrolled loop, static reg names).
// LDS holds A only: 2 x 32 KiB dbuf; per K-tile LDS reads 192->128 KB,
// stage-writes 64->32 KB. B traffic rides the ~idle vmem/L2 pipe.
// Sync per tile: issue [stageA(t+1) x4, gloadB(t+1) x8]; compute; vmcnt(8)
// (FIFO: retires the 4 A-stage loads, leaves 8 B in flight); s_barrier.
// Compiler auto-waits B regs before first use (aged one full tile).

template<int K>
__device__ inline void stage_halfA(char* ldsX, const u16* __restrict__ G, int grow0,
                                   int k0, int h, int wave, int lrow8, int slot8,
                                   int clampR) {
  #pragma unroll
  for (int j = 0; j < 2; ++j) {
    const int lrow = h * 128 + j * 64 + wave * 8;  // wave-uniform
    int gr = grow0 + lrow + lrow8;
    gr = gr < clampR ? gr : clampR - 1;
    gload_lds16(G + (size_t)gr * K + k0 + slot8, ldsX + lrow * 128);
  }
}

#define LOAD_A(MH)                                                              \
  _Pragma("unroll") for (int mf = 0; mf < 4; ++mf) {                            \
    af[mf][0] = *(const bf16x8*)(cA + ((MH) * 128 + mf * 16) * 128 + kc0);      \
    af[mf][1] = *(const bf16x8*)(cA + ((MH) * 128 + mf * 16) * 128 + kc1);      \
  }
// load all 4 n-frags x 2 k-slices of B for one tile into register SET
#define GLOADB(SET, BT, K0)                                                     \
  _Pragma("unroll") for (int n4 = 0; n4 < 4; ++n4) {                            \
    const u16* bp = (BT) + (size_t)(colBq + (n4 >> 1) * 128 + (n4 & 1) * 16) * K \
                    + (K0) + kgE;                                               \
    SET[n4][0] = *(const bf16x8*)(bp);                                          \
    SET[n4][1] = *(const bf16x8*)(bp + 32);                                     \
  }
#define QUAD(MH, SET, NH)                                                       \
  _Pragma("unroll") for (int mf = 0; mf < 4; ++mf)                              \
  _Pragma("unroll") for (int nf = 0; nf < 2; ++nf) {                            \
    acc[(MH)*4+mf][(NH)*2+nf] = __builtin_amdgcn_mfma_f32_16x16x32_bf16(        \
        af[mf][0], SET[(NH)*2+nf][0], acc[(MH)*4+mf][(NH)*2+nf], 0, 0, 0);      \
    acc[(MH)*4+mf][(NH)*2+nf] = __builtin_amdgcn_mfma_f32_16x16x32_bf16(        \
        af[mf][1], SET[(NH)*2+nf][1], acc[(MH)*4+mf][(NH)*2+nf], 0, 0, 0);      \
  }

// one K-tile: issue next-tile staging+B, compute current from LDS(A)+SET
#define TILE_BODY(t, CURSET, NXTSET)                                            \
  {                                                                             \
    const int cur = (t) & 1;                                                    \
    const char* cA = pA0 + cur * 32768;                                         \
    char* nA = lds + (cur ^ 1) * 32768;                                         \
    const int vt = ((t) + 1 < NT) ? (t) + 1 : NT - 1;                           \
    const u16* sA; const u16* sB; int sk0;                                      \
    if (DUAL && vt >= NTp) { sA = A2; sB = B2t; sk0 = (vt - NTp) * 64; }        \
    else                   { sA = A1; sB = B1t; sk0 = vt * 64; }                \
    stage_halfA<K>(nA, sA, rowBase, sk0, 0, wave, lrow8, slot8, M);             \
    stage_halfA<K>(nA, sA, rowBase, sk0, 1, wave, lrow8, slot8, M);             \
    GLOADB(NXTSET, sB, sk0);                                                    \
    LOAD_A(0);                                                                  \
    QUAD(0, CURSET, 0);                                                         \
    QUAD(0, CURSET, 1);                                                         \
    LOAD_A(1);                                                                  \
    QUAD(1, CURSET, 1);                                                         \
    QUAD(1, CURSET, 0);                                                         \
    asm volatile("s_waitcnt vmcnt(8)" ::: "memory");                            \
    __builtin_amdgcn_s_barrier();                                               \
  }

template<int K, bool DUAL, bool EPI, bool OUT_F32>
__global__ __launch_bounds__(512, 2)
void gemmBD(const u16* __restrict__ A1, const u16* __restrict__ A2,
            const u16* __restrict__ B1t, const u16* __restrict__ B2t,
            const float* __restrict__ bias, void* __restrict__ Cout,
            int M, int Nc, int tilesN) {
  __shared__ __align__(16) char lds[65536];   // A only, dbuf 2 x 32 KiB
  constexpr int NTp = K / 64;
  constexpr int NT = DUAL ? 2 * NTp : NTp;    // even for all call sites

  // bijective XCD swizzle (gridDim.x % 8 == 0 for all call sites)
  const int nwg = gridDim.x;
  const int bid = blockIdx.x;
  const int wg = (bid & 7) * (nwg >> 3) + (bid >> 3);
  const int bx = wg % tilesN, by = wg / tilesN;
  const int rowBase = by * 256, colBase = bx * 256;

  const int tid = threadIdx.x;
  const int lane = tid & 63;
  const int wave = tid >> 6;
  const int wm = wave >> 2, wn = wave & 3;
  const int r = lane & 15, kg = lane >> 4;
  const int sw = (r & 7) << 4;
  const int kc0 = (kg * 16) ^ sw;
  const int kc1 = (64 + kg * 16) ^ sw;
  const int slot8 = ((lane & 7) ^ ((lane >> 3) & 7)) * 8;  // global chunk, elems
  const int lrow8 = lane >> 3;
  const int colBq = colBase + wn * 32 + r;   // per-lane B column base
  const int kgE = kg * 8;                    // per-lane B k offset (elems)

  char* const pA0 = lds + (wm * 64 + r) * 128;

  f32x4 acc[8][4];
  #pragma unroll
  for (int m = 0; m < 8; ++m)
    #pragma unroll
    for (int n = 0; n < 4; ++n) acc[m][n] = (f32x4){0.f, 0.f, 0.f, 0.f};

  bf16x8 af[4][2], bX[4][2], bY[4][2];

  // prologue: stage A(0) + load B(0) into set X
  stage_halfA<K>(lds, A1, rowBase, 0, 0, wave, lrow8, slot8, M);
  stage_halfA<K>(lds, A1, rowBase, 0, 1, wave, lrow8, slot8, M);
  GLOADB(bX, B1t, 0);
  asm volatile("s_waitcnt vmcnt(8)" ::: "memory");  // A(0) staged (B still in flight)
  __builtin_amdgcn_s_barrier();

  #pragma unroll 1
  for (int t = 0; t < NT; t += 2) {
    TILE_BODY(t,     bX, bY);
    TILE_BODY(t + 1, bY, bX);
  }

  asm volatile("s_waitcnt vmcnt(0)" ::: "memory");  // drain stray prefetch

  // epilogue: [bias + relu] + store (C map: col=lane&15, row=(lane>>4)*4+reg)
  const int q = lane >> 4;
  #pragma unroll
  for (int m = 0; m < 8; ++m) {
    int row = rowBase + (m >> 2) * 128 + wm * 64 + (m & 3) * 16 + q * 4;
    #pragma unroll
    for (int n = 0; n < 4; ++n) {
      int col = colBase + (n >> 1) * 128 + wn * 32 + (n & 1) * 16 + r;
      float bv = EPI ? bias[col] : 0.f;
      #pragma unroll
      for (int reg = 0; reg < 4; ++reg) {
        if (row + reg < M) {
          float v = acc[m][n][reg];
          if constexpr (EPI) v = fmaxf(v + bv, 0.f);
          if constexpr (OUT_F32)
            ((float*)Cout)[(size_t)(row + reg) * Nc + col] = v;
          else
            ((u16*)Cout)[(size_t)(row + reg) * Nc + col] = f2bf(v);
        }
      }
    }
  }
}

// ---------------- launch ----------------
extern "C" void kernel_launch(void* const* d_in, const int* in_sizes, int n_in,
                              void* d_out, int out_size, void* d_ws, size_t ws_size,
                              hipStream_t stream) {
  const float* x   = (const float*)d_in[0];
  const int*   eix = (const int*)d_in[2];
  const float* W1l = (const float*)d_in[3];
  const float* W1r = (const float*)d_in[4];
  const float* b1  = (const float*)d_in[5];
  const float* W2l = (const float*)d_in[6];
  const float* W2r = (const float*)d_in[7];
  const float* b2  = (const float*)d_in[8];
  const float* W3l = (const float*)d_in[9];
  const float* W3r = (const float*)d_in[10];
  const float* b3  = (const float*)d_in[11];

  char* ws = (char*)d_ws;
  size_t off = 0;
  auto alloc = [&](size_t bytes) -> char* {
    char* p = ws + off;
    off += (bytes + 255) & ~(size_t)255;
    return p;
  };
  int* flag   = (int*)alloc(4);
  int* srcA   = (int*)alloc((size_t)EE * 4);
  int* dstA   = (int*)alloc((size_t)EE * 4);
  int* bucket = (int*)alloc((size_t)EE * 4);
  int* cnt    = (int*)alloc((size_t)NN * 4);
  int* offs   = (int*)alloc((size_t)NN * 4);
  int* cursor = (int*)alloc((size_t)NN * 4);
  u16* xb     = (u16*)alloc((size_t)NN * 128 * 2);
  u16* mean1  = (u16*)alloc((size_t)NN * 128 * 2);
  u16* W1lT   = (u16*)alloc((size_t)2048 * 128 * 2);
  u16* W1rT   = (u16*)alloc((size_t)2048 * 128 * 2);
  u16* W2lT   = (u16*)alloc((size_t)2048 * 2048 * 2);
  u16* W2rT   = (u16*)alloc((size_t)2048 * 2048 * 2);
  u16* W3lT   = (u16*)alloc((size_t)1024 * 2048 * 2);  // contiguous with W3rT:
  u16* W3rT   = (u16*)alloc((size_t)1024 * 2048 * 2);  // [W3lT;W3rT] = 2048xK
  u16* bufA   = (u16*)alloc((size_t)NN * 2048 * 2);  // h1, later Y
  u16* bufB   = (u16*)alloc((size_t)NN * 2048 * 2);  // h2
  u16* mean2  = (u16*)d_out;                         // d_out reused as scratch

  // edges -> int32 src/dst
  detect_i64<<<1, 256, 0, stream>>>(eix, flag);
  conv_edges<<<(EE + 255) / 256, 256, 0, stream>>>(eix, flag, srcA, dstA);

  // CSR
  hipMemsetAsync(cnt, 0, (size_t)NN * 4, stream);
  count_edges<<<(EE + 255) / 256, 256, 0, stream>>>(dstA, cnt);
  scan_counts<<<1, 1024, 0, stream>>>(cnt, offs, cursor);
  fill_buckets<<<(EE + 255) / 256, 256, 0, stream>>>(srcA, dstA, cursor, bucket);

  // conversions
  cvt_bf16<<<(NN * 128 / 4 + 255) / 256, 256, 0, stream>>>(x, xb, NN * 128 / 4);
  transposeW<<<dim3(2048 / 32, 128 / 32), dim3(32, 8), 0, stream>>>(W1l, W1lT, 128, 2048);
  transposeW<<<dim3(2048 / 32, 128 / 32), dim3(32, 8), 0, stream>>>(W1r, W1rT, 128, 2048);
  transposeW<<<dim3(2048 / 32, 2048 / 32), dim3(32, 8), 0, stream>>>(W2l, W2lT, 2048, 2048);
  transposeW<<<dim3(2048 / 32, 2048 / 32), dim3(32, 8), 0, stream>>>(W2r, W2rT, 2048, 2048);
  transposeW<<<dim3(1024 / 32, 2048 / 32), dim3(32, 8), 0, stream>>>(W3l, W3lT, 2048, 1024);
  transposeW<<<dim3(1024 / 32, 2048 / 32), dim3(32, 8), 0, stream>>>(W3r, W3rT, 2048, 1024);

  const int tilesM = (NN + 255) / 256;  // 196

  // layer 1: h1 = relu(mean1@W1l + x@W1r + b1)
  agg_mean<128><<<NN, 64, 0, stream>>>(xb, offs, cnt, bucket, mean1);
  gemmBD<128, true, true, false><<<tilesM * 8, 512, 0, stream>>>(
      mean1, xb, W1lT, W1rT, b1, bufA, NN, 2048, 8);

  // layer 2: h2 = relu(mean2@W2l + h1@W2r + b2)
  agg_mean<2048><<<NN, 256, 0, stream>>>(bufA, offs, cnt, bucket, mean2);
  gemmBD<2048, true, true, false><<<tilesM * 8, 512, 0, stream>>>(
      mean2, bufA, W2lT, W2rT, b2, bufB, NN, 2048, 8);

  // layer 3 (restructured): Y = h2@[W3l;W3r] (single-source, no epilogue);
  // then out = l2norm(relu(mean(Y_l) + Y_r + b3))
  gemmBD<2048, false, false, false><<<tilesM * 8, 512, 0, stream>>>(
      bufB, nullptr, W3lT, nullptr, nullptr, bufA, NN, 2048, 8);
  agg_add_norm<<<NN, 256, 0, stream>>>(bufA, offs, cnt, bucket, b3, (float*)d_out);
}

// Round 12
// 2158.249 us; speedup vs baseline: 1.1897x; 1.1897x over previous
//
#include <hip/hip_runtime.h>
#include <stdint.h>

#define NN 50000
#define EE 400000

typedef unsigned short u16;
typedef __attribute__((ext_vector_type(8))) short bf16x8;
typedef __attribute__((ext_vector_type(16))) float f32x16;
typedef __attribute__((address_space(3))) uint32_t lds_u32_t;
typedef __attribute__((address_space(1))) uint32_t glob_u32_t;

__device__ inline float bf2f(u16 u) {
  union { uint32_t i; float f; } x; x.i = ((uint32_t)u) << 16; return x.f;
}
__device__ inline u16 f2bf(float f) {
  union { float f; uint32_t i; } x; x.f = f;
  x.i += 0x7fffu + ((x.i >> 16) & 1u);   // RNE
  return (u16)(x.i >> 16);
}
__device__ inline void gload_lds16(const void* g, void* l) {
  __builtin_amdgcn_global_load_lds((const glob_u32_t*)g, (lds_u32_t*)l, 16, 0, 0);
}

// ---------------- edge dtype detect + normalize ----------------
__global__ void detect_i64(const int* __restrict__ e, int* __restrict__ flag) {
  __shared__ int sh[256];
  int t = threadIdx.x;
  int v = 0;
  for (int i = t; i < 4096; i += 256) v |= e[2 * i + 1];
  sh[t] = v; __syncthreads();
  for (int s = 128; s > 0; s >>= 1) { if (t < s) sh[t] |= sh[t + s]; __syncthreads(); }
  if (t == 0) flag[0] = (sh[0] == 0) ? 1 : 0;   // all high words zero -> int64
}

__global__ void conv_edges(const int* __restrict__ e, const int* __restrict__ flag,
                           int* __restrict__ src, int* __restrict__ dst) {
  int i = blockIdx.x * 256 + threadIdx.x;
  if (i >= EE) return;
  if (flag[0]) { src[i] = e[2 * i]; dst[i] = e[2 * (EE + i)]; }
  else         { src[i] = e[i];     dst[i] = e[EE + i]; }
}

// ---------------- CSR build ----------------
__global__ void count_edges(const int* __restrict__ dst, int* __restrict__ cnt) {
  int i = blockIdx.x * 256 + threadIdx.x;
  if (i < EE) atomicAdd(&cnt[dst[i]], 1);
}

__global__ void scan_counts(const int* __restrict__ cnt, int* __restrict__ offs,
                            int* __restrict__ cursor) {
  __shared__ int sh[1024];
  __shared__ int carry_sh;
  int tid = threadIdx.x;
  if (tid == 0) carry_sh = 0;
  __syncthreads();
  int nChunks = (NN + 1023) / 1024;
  for (int c = 0; c < nChunks; ++c) {
    int idx = c * 1024 + tid;
    int v = (idx < NN) ? cnt[idx] : 0;
    sh[tid] = v; __syncthreads();
    for (int off = 1; off < 1024; off <<= 1) {
      int t = (tid >= off) ? sh[tid - off] : 0;
      __syncthreads();
      sh[tid] += t;
      __syncthreads();
    }
    int incl = sh[tid];
    int excl = incl - v + carry_sh;
    if (idx < NN) { offs[idx] = excl; cursor[idx] = excl; }
    __syncthreads();
    if (tid == 0) carry_sh += sh[1023];
    __syncthreads();
  }
}

__global__ void fill_buckets(const int* __restrict__ src, const int* __restrict__ dst,
                             int* __restrict__ cursor, int* __restrict__ bucket) {
  int i = blockIdx.x * 256 + threadIdx.x;
  if (i >= EE) return;
  int p = atomicAdd(&cursor[dst[i]], 1);
  bucket[p] = src[i];
}

// ---------------- fp32 -> bf16 conversions ----------------
__global__ void cvt_bf16(const float* __restrict__ in, u16* __restrict__ out, int n4) {
  int i = blockIdx.x * 256 + threadIdx.x;
  if (i >= n4) return;
  float4 v = ((const float4*)in)[i];
  u16 o[4] = { f2bf(v.x), f2bf(v.y), f2bf(v.z), f2bf(v.w) };
  uint2 pack;
  pack.x = (uint32_t)o[0] | ((uint32_t)o[1] << 16);
  pack.y = (uint32_t)o[2] | ((uint32_t)o[3] << 16);
  ((uint2*)out)[i] = pack;
}

// W [K][Nc] fp32 -> Wt [Nc][K] bf16
__global__ void transposeW(const float* __restrict__ W, u16* __restrict__ Wt,
                           int K, int Nc) {
  __shared__ float tile[32][33];
  int n0 = blockIdx.x * 32, k0 = blockIdx.y * 32;
  int tx = threadIdx.x, ty = threadIdx.y;  // 32 x 8
  #pragma unroll
  for (int i = 0; i < 4; ++i)
    tile[ty + i * 8][tx] = W[(size_t)(k0 + ty + i * 8) * Nc + n0 + tx];
  __syncthreads();
  #pragma unroll
  for (int i = 0; i < 4; ++i)
    Wt[(size_t)(n0 + ty + i * 8) * K + k0 + tx] = f2bf(tile[tx][ty + i * 8]);
}

// ---------------- mean aggregation (CSR gather) ----------------
template<int D>
__global__ void agg_mean(const u16* __restrict__ h, const int* __restrict__ offs,
                         const int* __restrict__ cnt, const int* __restrict__ bucket,
                         u16* __restrict__ outp) {
  int node = blockIdx.x;
  int t = threadIdx.x;
  int base = t * 8;
  if (base >= D) return;
  int start = offs[node];
  int c = cnt[node];
  float acc[8];
  #pragma unroll
  for (int i = 0; i < 8; ++i) acc[i] = 0.f;
  for (int j = 0; j < c; ++j) {
    int s = bucket[start + j];
    uint4 q = *(const uint4*)(h + (size_t)s * D + base);
    acc[0] += bf2f((u16)(q.x & 0xffff)); acc[1] += bf2f((u16)(q.x >> 16));
    acc[2] += bf2f((u16)(q.y & 0xffff)); acc[3] += bf2f((u16)(q.y >> 16));
    acc[4] += bf2f((u16)(q.z & 0xffff)); acc[5] += bf2f((u16)(q.z >> 16));
    acc[6] += bf2f((u16)(q.w & 0xffff)); acc[7] += bf2f((u16)(q.w >> 16));
  }
  float inv = 1.0f / fmaxf((float)c, 1.0f);
  uint4 o;
  o.x = (uint32_t)f2bf(acc[0] * inv) | ((uint32_t)f2bf(acc[1] * inv) << 16);
  o.y = (uint32_t)f2bf(acc[2] * inv) | ((uint32_t)f2bf(acc[3] * inv) << 16);
  o.z = (uint32_t)f2bf(acc[4] * inv) | ((uint32_t)f2bf(acc[5] * inv) << 16);
  o.w = (uint32_t)f2bf(acc[6] * inv) | ((uint32_t)f2bf(acc[7] * inv) << 16);
  *(uint4*)(outp + (size_t)node * D + base) = o;
}

// ---- fused layer-3 tail: out = l2norm(relu(mean(Y_l[nbrs]) + Y_r + b3)) ----
__global__ void agg_add_norm(const u16* __restrict__ Y, const int* __restrict__ offs,
                             const int* __restrict__ cnt, const int* __restrict__ bucket,
                             const float* __restrict__ b3, float* __restrict__ outp) {
  int node = blockIdx.x;
  int t = threadIdx.x;
  int base = t * 4;  // 0..1023
  int start = offs[node];
  int c = cnt[node];
  float acc[4] = {0.f, 0.f, 0.f, 0.f};
  for (int j = 0; j < c; ++j) {
    int s = bucket[start + j];
    uint2 q = *(const uint2*)(Y + (size_t)s * 2048 + base);
    acc[0] += bf2f((u16)(q.x & 0xffff)); acc[1] += bf2f((u16)(q.x >> 16));
    acc[2] += bf2f((u16)(q.y & 0xffff)); acc[3] += bf2f((u16)(q.y >> 16));
  }
  float inv = 1.0f / fmaxf((float)c, 1.0f);
  uint2 qr = *(const uint2*)(Y + (size_t)node * 2048 + 1024 + base);
  float yr[4] = { bf2f((u16)(qr.x & 0xffff)), bf2f((u16)(qr.x >> 16)),
                  bf2f((u16)(qr.y & 0xffff)), bf2f((u16)(qr.y >> 16)) };
  float4 bv = *(const float4*)(b3 + base);
  float v[4];
  v[0] = fmaxf(acc[0] * inv + yr[0] + bv.x, 0.f);
  v[1] = fmaxf(acc[1] * inv + yr[1] + bv.y, 0.f);
  v[2] = fmaxf(acc[2] * inv + yr[2] + bv.z, 0.f);
  v[3] = fmaxf(acc[3] * inv + yr[3] + bv.w, 0.f);
  float ss = v[0] * v[0] + v[1] * v[1] + v[2] * v[2] + v[3] * v[3];
  #pragma unroll
  for (int off = 32; off > 0; off >>= 1) ss += __shfl_down(ss, off);
  __shared__ float sw[4];
  int lane = t & 63, w = t >> 6;
  if (lane == 0) sw[w] = ss;
  __syncthreads();
  float total = sw[0] + sw[1] + sw[2] + sw[3];
  float scale = 1.0f / fmaxf(sqrtf(total), 1e-12f);
  float4 o = { v[0] * scale, v[1] * scale, v[2] * scale, v[3] * scale };
  *(float4*)(outp + (size_t)node * 1024 + base) = o;
}

// ------------- 256x256 4-phase GEMM, 32x32x16 MFMA core (R12) ---------------
// C[M,Nc] = [relu](A1@B1t' [+ A2@B2t'] [+ bias]), A bf16 [M,K], Bt bf16 [Nc][K]
// R3 schedule/staging byte-identical; only the MFMA shape changes:
// 32x32x16 (m119: 2495 TF ceiling vs 2176 for 16x16x32; ~2048 vs 2483
// cyc/K-tile matrix time; half the MFMA instructions).
// Wave output 128x64 = 4 Mtiles(32) x 2 Ntiles(32); acc[4][2] f32x16 = 128 VGPR.
// A-frag: lane holds row=lane&31, k=(lane>>5)*8..+8 (16B contiguous -> same
// ds_read_b128 + row&7 swizzle as before). B-frag symmetric from Bt.
// C/D map (m74/m101): col=lane&31, row=(reg&3)+8*(reg>>2)+4*(lane>>5).

template<int K>
__device__ inline void stage_half(char* ldsX, const u16* __restrict__ G, int grow0,
                                  int k0, int h, int wave, int lrow8, int slot8,
                                  int clampR) {
  #pragma unroll
  for (int j = 0; j < 2; ++j) {
    const int lrow = h * 128 + j * 64 + wave * 8;  // wave-uniform
    int gr = grow0 + lrow + lrow8;
    gr = gr < clampR ? gr : clampR - 1;
    gload_lds16(G + (size_t)gr * K + k0 + slot8, ldsX + lrow * 128);
  }
}

// A-frags for half MH: 2 Mtiles x 4 k-steps
#define LOAD_A(MH)                                                              \
  _Pragma("unroll") for (int mt = 0; mt < 2; ++mt)                              \
  _Pragma("unroll") for (int ks = 0; ks < 4; ++ks)                              \
    af[mt][ks] = *(const bf16x8*)(cA + ((MH) * 128 + mt * 32) * 128             \
                                  + ((ks * 32 + khE) ^ swz));
// B-frags for half NH: 1 Ntile x 4 k-steps
#define LOAD_B(DST, NH)                                                         \
  _Pragma("unroll") for (int ks = 0; ks < 4; ++ks)                              \
    DST[ks] = *(const bf16x8*)(cB + (NH) * 16384 + ((ks * 32 + khE) ^ swz));
// 8 MFMAs: 2 Mtiles x 4 k-steps into acc[MH*2+mt][NH]
#define QUAD(MH, BREG, NH)                                                      \
  _Pragma("unroll") for (int mt = 0; mt < 2; ++mt)                              \
  _Pragma("unroll") for (int ks = 0; ks < 4; ++ks)                              \
    acc[(MH)*2+mt][NH] = __builtin_amdgcn_mfma_f32_32x32x16_bf16(               \
        af[mt][ks], BREG[ks], acc[(MH)*2+mt][NH], 0, 0, 0);

template<int K, bool DUAL, bool EPI, bool OUT_F32>
__global__ __launch_bounds__(512, 2)
void gemm2src(const u16* __restrict__ A1, const u16* __restrict__ A2,
              const u16* __restrict__ B1t, const u16* __restrict__ B2t,
              const float* __restrict__ bias, void* __restrict__ Cout,
              int M, int Nc, int tilesN) {
  __shared__ __align__(16) char lds[131072];
  constexpr int NTp = K / 64;
  constexpr int NT = DUAL ? 2 * NTp : NTp;

  // bijective XCD swizzle (gridDim.x % 8 == 0 for all call sites)
  const int nwg = gridDim.x;
  const int bid = blockIdx.x;
  const int wg = (bid & 7) * (nwg >> 3) + (bid >> 3);
  const int bx = wg % tilesN, by = wg / tilesN;
  const int rowBase = by * 256, colBase = bx * 256;

  const int tid = threadIdx.x;
  const int lane = tid & 63;
  const int wave = tid >> 6;
  const int wm = wave >> 2, wn = wave & 3;
  const int rA = lane & 31;          // fragment row/col within 32-tile
  const int kh = lane >> 5;          // k-half (0/1)
  const int khE = kh * 16;           // k-half byte offset
  const int swz = (rA & 7) << 4;     // LDS slot swizzle (row&7)
  const int slot8 = ((lane & 7) ^ ((lane >> 3) & 7)) * 8;  // staging chunk, elems
  const int lrow8 = lane >> 3;

  char* const pA0 = lds + (wm * 64 + rA) * 128;
  char* const pB0 = lds + 32768 + (wn * 32 + rA) * 128;

  f32x16 acc[4][2];
  #pragma unroll
  for (int m = 0; m < 4; ++m)
    #pragma unroll
    for (int n = 0; n < 2; ++n)
      #pragma unroll
      for (int e = 0; e < 16; ++e) acc[m][n][e] = 0.f;

  bf16x8 af[2][4], b0[4], b1[4];

  // prologue: stage tile0 in steady-state order A-h0, B-h0, B-h1, A-h1
  stage_half<K>(lds,         A1,  rowBase, 0, 0, wave, lrow8, slot8, M);
  stage_half<K>(lds + 32768, B1t, colBase, 0, 0, wave, lrow8, slot8, Nc);
  stage_half<K>(lds + 32768, B1t, colBase, 0, 1, wave, lrow8, slot8, Nc);
  stage_half<K>(lds,         A1,  rowBase, 0, 1, wave, lrow8, slot8, M);
  asm volatile("s_waitcnt vmcnt(4)" ::: "memory");  // A-h0 + B-h0 complete
  __builtin_amdgcn_s_barrier();

  for (int t = 0; t < NT; ++t) {
    const int cur = t & 1;
    const char* cA = pA0 + cur * 65536;
    const char* cB = pB0 + cur * 65536;
    char* nA = lds + (cur ^ 1) * 65536;
    char* nB = nA + 32768;
    const int vt = (t + 1 < NT) ? t + 1 : NT - 1;
    const u16* sA; const u16* sB; int sk0;
    if (DUAL && vt >= NTp) { sA = A2; sB = B2t; sk0 = (vt - NTp) * 64; }
    else                   { sA = A1; sB = B1t; sk0 = vt * 64; }

    // ---- phase A: quad (0,0) [A-h0,B-h0]; stage A-h0(t+1); vmcnt(4) ----
    LOAD_A(0); LOAD_B(b0, 0);
    stage_half<K>(nA, sA, rowBase, sk0, 0, wave, lrow8, slot8, M);
    __builtin_amdgcn_s_barrier();
    asm volatile("s_waitcnt lgkmcnt(0)" ::: "memory");
    __builtin_amdgcn_s_setprio(1);
    QUAD(0, b0, 0);
    __builtin_amdgcn_s_setprio(0);
    asm volatile("s_waitcnt vmcnt(4)" ::: "memory");  // B-h1(cur tile) done
    __builtin_amdgcn_s_barrier();

    // ---- phase B: quad (0,1) [A-h0,B-h1]; stage B-h0(t+1); vmcnt(4) ----
    LOAD_B(b1, 1);
    stage_half<K>(nB, sB, colBase, sk0, 0, wave, lrow8, slot8, Nc);
    __builtin_amdgcn_s_barrier();
    asm volatile("s_waitcnt lgkmcnt(0)" ::: "memory");
    __builtin_amdgcn_s_setprio(1);
    QUAD(0, b1, 1);
    __builtin_amdgcn_s_setprio(0);
    asm volatile("s_waitcnt vmcnt(4)" ::: "memory");  // A-h1(cur tile) done
    __builtin_amdgcn_s_barrier();

    // ---- phase C: quad (1,1) [A-h1,B-h1]; stage B-h1(t+1); no vm wait ----
    LOAD_A(1);
    stage_half<K>(nB, sB, colBase, sk0, 1, wave, lrow8, slot8, Nc);
    __builtin_amdgcn_s_barrier();
    asm volatile("s_waitcnt lgkmcnt(0)" ::: "memory");
    __builtin_amdgcn_s_setprio(1);
    QUAD(1, b1, 1);
    __builtin_amdgcn_s_setprio(0);
    __builtin_amdgcn_s_barrier();

    // ---- phase D: quad (1,0) [regs only]; stage A-h1(t+1); vmcnt(4) ----
    stage_half<K>(nA, sA, rowBase, sk0, 1, wave, lrow8, slot8, M);
    __builtin_amdgcn_s_barrier();
    __builtin_amdgcn_s_setprio(1);
    QUAD(1, b0, 0);
    __builtin_amdgcn_s_setprio(0);
    asm volatile("s_waitcnt vmcnt(4)" ::: "memory");  // A-h0+B-h0(next) done
    __builtin_amdgcn_s_barrier();
  }

  // drain stray prefetch before exit
  asm volatile("s_waitcnt vmcnt(0)" ::: "memory");

  // epilogue: C map col=lane&31, row=(reg&3)+8*(reg>>2)+4*(lane>>5)
  #pragma unroll
  for (int mq = 0; mq < 4; ++mq) {
    int rowT = rowBase + (mq >> 1) * 128 + wm * 64 + (mq & 1) * 32 + 4 * kh;
    #pragma unroll
    for (int nt = 0; nt < 2; ++nt) {
      int col = colBase + nt * 128 + wn * 32 + rA;
      float bv = EPI ? bias[col] : 0.f;
      #pragma unroll
      for (int reg = 0; reg < 16; ++reg) {
        int row = rowT + (reg & 3) + 8 * (reg >> 2);
        if (row < M) {
          float v = acc[mq][nt][reg];
          if constexpr (EPI) v = fmaxf(v + bv, 0.f);
          if constexpr (OUT_F32)
            ((float*)Cout)[(size_t)row * Nc + col] = v;
          else
            ((u16*)Cout)[(size_t)row * Nc + col] = f2bf(v);
        }
      }
    }
  }
}

// ---------------- launch ----------------
extern "C" void kernel_launch(void* const* d_in, const int* in_sizes, int n_in,
                              void* d_out, int out_size, void* d_ws, size_t ws_size,
                              hipStream_t stream) {
  const float* x   = (const float*)d_in[0];
  const int*   eix = (const int*)d_in[2];
  const float* W1l = (const float*)d_in[3];
  const float* W1r = (const float*)d_in[4];
  const float* b1  = (const float*)d_in[5];
  const float* W2l = (const float*)d_in[6];
  const float* W2r = (const float*)d_in[7];
  const float* b2  = (const float*)d_in[8];
  const float* W3l = (const float*)d_in[9];
  const float* W3r = (const float*)d_in[10];
  const float* b3  = (const float*)d_in[11];

  char* ws = (char*)d_ws;
  size_t off = 0;
  auto alloc = [&](size_t bytes) -> char* {
    char* p = ws + off;
    off += (bytes + 255) & ~(size_t)255;
    return p;
  };
  int* flag   = (int*)alloc(4);
  int* srcA   = (int*)alloc((size_t)EE * 4);
  int* dstA   = (int*)alloc((size_t)EE * 4);
  int* bucket = (int*)alloc((size_t)EE * 4);
  int* cnt    = (int*)alloc((size_t)NN * 4);
  int* offs   = (int*)alloc((size_t)NN * 4);
  int* cursor = (int*)alloc((size_t)NN * 4);
  u16* xb     = (u16*)alloc((size_t)NN * 128 * 2);
  u16* mean1  = (u16*)alloc((size_t)NN * 128 * 2);
  u16* W1lT   = (u16*)alloc((size_t)2048 * 128 * 2);
  u16* W1rT   = (u16*)alloc((size_t)2048 * 128 * 2);
  u16* W2lT   = (u16*)alloc((size_t)2048 * 2048 * 2);
  u16* W2rT   = (u16*)alloc((size_t)2048 * 2048 * 2);
  u16* W3lT   = (u16*)alloc((size_t)1024 * 2048 * 2);  // contiguous with W3rT:
  u16* W3rT   = (u16*)alloc((size_t)1024 * 2048 * 2);  // [W3lT;W3rT] = 2048xK
  u16* bufA   = (u16*)alloc((size_t)NN * 2048 * 2);  // h1, later Y
  u16* bufB   = (u16*)alloc((size_t)NN * 2048 * 2);  // h2
  u16* mean2  = (u16*)d_out;                         // d_out reused as scratch

  // edges -> int32 src/dst
  detect_i64<<<1, 256, 0, stream>>>(eix, flag);
  conv_edges<<<(EE + 255) / 256, 256, 0, stream>>>(eix, flag, srcA, dstA);

  // CSR
  hipMemsetAsync(cnt, 0, (size_t)NN * 4, stream);
  count_edges<<<(EE + 255) / 256, 256, 0, stream>>>(dstA, cnt);
  scan_counts<<<1, 1024, 0, stream>>>(cnt, offs, cursor);
  fill_buckets<<<(EE + 255) / 256, 256, 0, stream>>>(srcA, dstA, cursor, bucket);

  // conversions
  cvt_bf16<<<(NN * 128 / 4 + 255) / 256, 256, 0, stream>>>(x, xb, NN * 128 / 4);
  transposeW<<<dim3(2048 / 32, 128 / 32), dim3(32, 8), 0, stream>>>(W1l, W1lT, 128, 2048);
  transposeW<<<dim3(2048 / 32, 128 / 32), dim3(32, 8), 0, stream>>>(W1r, W1rT, 128, 2048);
  transposeW<<<dim3(2048 / 32, 2048 / 32), dim3(32, 8), 0, stream>>>(W2l, W2lT, 2048, 2048);
  transposeW<<<dim3(2048 / 32, 2048 / 32), dim3(32, 8), 0, stream>>>(W2r, W2rT, 2048, 2048);
  transposeW<<<dim3(1024 / 32, 2048 / 32), dim3(32, 8), 0, stream>>>(W3l, W3lT, 2048, 1024);
  transposeW<<<dim3(1024 / 32, 2048 / 32), dim3(32, 8), 0, stream>>>(W3r, W3rT, 2048, 1024);

  const int tilesM = (NN + 255) / 256;  // 196

  // layer 1: h1 = relu(mean1@W1l + x@W1r + b1)
  agg_mean<128><<<NN, 64, 0, stream>>>(xb, offs, cnt, bucket, mean1);
  gemm2src<128, true, true, false><<<tilesM * 8, 512, 0, stream>>>(
      mean1, xb, W1lT, W1rT, b1, bufA, NN, 2048, 8);

  // layer 2: h2 = relu(mean2@W2l + h1@W2r + b2)
  agg_mean<2048><<<NN, 256, 0, stream>>>(bufA, offs, cnt, bucket, mean2);
  gemm2src<2048, true, true, false><<<tilesM * 8, 512, 0, stream>>>(
      mean2, bufA, W2lT, W2rT, b2, bufB, NN, 2048, 8);

  // layer 3 (restructured): Y = h2@[W3l;W3r] (single-source, no epilogue);
  // then out = l2norm(relu(mean(Y_l) + Y_r + b3))
  gemm2src<2048, false, false, false><<<tilesM * 8, 512, 0, stream>>>(
      bufB, nullptr, W3lT, nullptr, nullptr, bufA, NN, 2048, 8);
  agg_add_norm<<<NN, 256, 0, stream>>>(bufA, offs, cnt, bucket, b3, (float*)d_out);
}

// Round 13
// 1979.336 us; speedup vs baseline: 1.2973x; 1.0904x over previous
//
#include <hip/hip_runtime.h>
#include <stdint.h>

#define NN 50000
#define EE 400000

typedef unsigned short u16;
typedef __attribute__((ext_vector_type(8))) short bf16x8;
typedef __attribute__((ext_vector_type(4))) float f32x4;
typedef __attribute__((address_space(3))) uint32_t lds_u32_t;
typedef __attribute__((address_space(1))) uint32_t glob_u32_t;

__device__ inline float bf2f(u16 u) {
  union { uint32_t i; float f; } x; x.i = ((uint32_t)u) << 16; return x.f;
}
__device__ inline u16 f2bf(float f) {
  union { float f; uint32_t i; } x; x.f = f;
  x.i += 0x7fffu + ((x.i >> 16) & 1u);   // RNE
  return (u16)(x.i >> 16);
}
__device__ inline void gload_lds16(const void* g, void* l) {
  __builtin_amdgcn_global_load_lds((const glob_u32_t*)g, (lds_u32_t*)l, 16, 0, 0);
}

// ---------------- edge dtype detect + normalize ----------------
__global__ void detect_i64(const int* __restrict__ e, int* __restrict__ flag) {
  __shared__ int sh[256];
  int t = threadIdx.x;
  int v = 0;
  for (int i = t; i < 4096; i += 256) v |= e[2 * i + 1];
  sh[t] = v; __syncthreads();
  for (int s = 128; s > 0; s >>= 1) { if (t < s) sh[t] |= sh[t + s]; __syncthreads(); }
  if (t == 0) flag[0] = (sh[0] == 0) ? 1 : 0;   // all high words zero -> int64
}

__global__ void conv_edges(const int* __restrict__ e, const int* __restrict__ flag,
                           int* __restrict__ src, int* __restrict__ dst) {
  int i = blockIdx.x * 256 + threadIdx.x;
  if (i >= EE) return;
  if (flag[0]) { src[i] = e[2 * i]; dst[i] = e[2 * (EE + i)]; }
  else         { src[i] = e[i];     dst[i] = e[EE + i]; }
}

// ---------------- CSR build ----------------
__global__ void count_edges(const int* __restrict__ dst, int* __restrict__ cnt) {
  int i = blockIdx.x * 256 + threadIdx.x;
  if (i < EE) atomicAdd(&cnt[dst[i]], 1);
}

__global__ void scan_counts(const int* __restrict__ cnt, int* __restrict__ offs,
                            int* __restrict__ cursor) {
  __shared__ int sh[1024];
  __shared__ int carry_sh;
  int tid = threadIdx.x;
  if (tid == 0) carry_sh = 0;
  __syncthreads();
  int nChunks = (NN + 1023) / 1024;
  for (int c = 0; c < nChunks; ++c) {
    int idx = c * 1024 + tid;
    int v = (idx < NN) ? cnt[idx] : 0;
    sh[tid] = v; __syncthreads();
    for (int off = 1; off < 1024; off <<= 1) {
      int t = (tid >= off) ? sh[tid - off] : 0;
      __syncthreads();
      sh[tid] += t;
      __syncthreads();
    }
    int incl = sh[tid];
    int excl = incl - v + carry_sh;
    if (idx < NN) { offs[idx] = excl; cursor[idx] = excl; }
    __syncthreads();
    if (tid == 0) carry_sh += sh[1023];
    __syncthreads();
  }
}

__global__ void fill_buckets(const int* __restrict__ src, const int* __restrict__ dst,
                             int* __restrict__ cursor, int* __restrict__ bucket) {
  int i = blockIdx.x * 256 + threadIdx.x;
  if (i >= EE) return;
  int p = atomicAdd(&cursor[dst[i]], 1);
  bucket[p] = src[i];
}

// ---------------- fp32 -> bf16 conversions ----------------
__global__ void cvt_bf16(const float* __restrict__ in, u16* __restrict__ out, int n4) {
  int i = blockIdx.x * 256 + threadIdx.x;
  if (i >= n4) return;
  float4 v = ((const float4*)in)[i];
  u16 o[4] = { f2bf(v.x), f2bf(v.y), f2bf(v.z), f2bf(v.w) };
  uint2 pack;
  pack.x = (uint32_t)o[0] | ((uint32_t)o[1] << 16);
  pack.y = (uint32_t)o[2] | ((uint32_t)o[3] << 16);
  ((uint2*)out)[i] = pack;
}

// W [K][Nc] fp32 -> Wt [Nc][K] bf16
__global__ void transposeW(const float* __restrict__ W, u16* __restrict__ Wt,
                           int K, int Nc) {
  __shared__ float tile[32][33];
  int n0 = blockIdx.x * 32, k0 = blockIdx.y * 32;
  int tx = threadIdx.x, ty = threadIdx.y;  // 32 x 8
  #pragma unroll
  for (int i = 0; i < 4; ++i)
    tile[ty + i * 8][tx] = W[(size_t)(k0 + ty + i * 8) * Nc + n0 + tx];
  __syncthreads();
  #pragma unroll
  for (int i = 0; i < 4; ++i)
    Wt[(size_t)(n0 + ty + i * 8) * K + k0 + tx] = f2bf(tile[tx][ty + i * 8]);
}

// ---------------- mean aggregation (CSR gather) ----------------
template<int D>
__global__ void agg_mean(const u16* __restrict__ h, const int* __restrict__ offs,
                         const int* __restrict__ cnt, const int* __restrict__ bucket,
                         u16* __restrict__ outp) {
  int node = blockIdx.x;
  int t = threadIdx.x;
  int base = t * 8;
  if (base >= D) return;
  int start = offs[node];
  int c = cnt[node];
  float acc[8];
  #pragma unroll
  for (int i = 0; i < 8; ++i) acc[i] = 0.f;
  for (int j = 0; j < c; ++j) {
    int s = bucket[start + j];
    uint4 q = *(const uint4*)(h + (size_t)s * D + base);
    acc[0] += bf2f((u16)(q.x & 0xffff)); acc[1] += bf2f((u16)(q.x >> 16));
    acc[2] += bf2f((u16)(q.y & 0xffff)); acc[3] += bf2f((u16)(q.y >> 16));
    acc[4] += bf2f((u16)(q.z & 0xffff)); acc[5] += bf2f((u16)(q.z >> 16));
    acc[6] += bf2f((u16)(q.w & 0xffff)); acc[7] += bf2f((u16)(q.w >> 16));
  }
  float inv = 1.0f / fmaxf((float)c, 1.0f);
  uint4 o;
  o.x = (uint32_t)f2bf(acc[0] * inv) | ((uint32_t)f2bf(acc[1] * inv) << 16);
  o.y = (uint32_t)f2bf(acc[2] * inv) | ((uint32_t)f2bf(acc[3] * inv) << 16);
  o.z = (uint32_t)f2bf(acc[4] * inv) | ((uint32_t)f2bf(acc[5] * inv) << 16);
  o.w = (uint32_t)f2bf(acc[6] * inv) | ((uint32_t)f2bf(acc[7] * inv) << 16);
  *(uint4*)(outp + (size_t)node * D + base) = o;
}

// ---- fused layer-3 tail: out = l2norm(relu(mean(Y_l[nbrs]) + Y_r + b3)) ----
// Y [NN][2048] bf16: cols 0..1023 = h2@W3l, cols 1024..2047 = h2@W3r.
__global__ void agg_add_norm(const u16* __restrict__ Y, const int* __restrict__ offs,
                             const int* __restrict__ cnt, const int* __restrict__ bucket,
                             const float* __restrict__ b3, float* __restrict__ outp) {
  int node = blockIdx.x;
  int t = threadIdx.x;
  int base = t * 4;  // 0..1023
  int start = offs[node];
  int c = cnt[node];
  float acc[4] = {0.f, 0.f, 0.f, 0.f};
  for (int j = 0; j < c; ++j) {
    int s = bucket[start + j];
    uint2 q = *(const uint2*)(Y + (size_t)s * 2048 + base);
    acc[0] += bf2f((u16)(q.x & 0xffff)); acc[1] += bf2f((u16)(q.x >> 16));
    acc[2] += bf2f((u16)(q.y & 0xffff)); acc[3] += bf2f((u16)(q.y >> 16));
  }
  float inv = 1.0f / fmaxf((float)c, 1.0f);
  uint2 qr = *(const uint2*)(Y + (size_t)node * 2048 + 1024 + base);
  float yr[4] = { bf2f((u16)(qr.x & 0xffff)), bf2f((u16)(qr.x >> 16)),
                  bf2f((u16)(qr.y & 0xffff)), bf2f((u16)(qr.y >> 16)) };
  float4 bv = *(const float4*)(b3 + base);
  float v[4];
  v[0] = fmaxf(acc[0] * inv + yr[0] + bv.x, 0.f);
  v[1] = fmaxf(acc[1] * inv + yr[1] + bv.y, 0.f);
  v[2] = fmaxf(acc[2] * inv + yr[2] + bv.z, 0.f);
  v[3] = fmaxf(acc[3] * inv + yr[3] + bv.w, 0.f);
  float ss = v[0] * v[0] + v[1] * v[1] + v[2] * v[2] + v[3] * v[3];
  #pragma unroll
  for (int off = 32; off > 0; off >>= 1) ss += __shfl_down(ss, off);
  __shared__ float sw[4];
  int lane = t & 63, w = t >> 6;
  if (lane == 0) sw[w] = ss;
  __syncthreads();
  float total = sw[0] + sw[1] + sw[2] + sw[3];
  float scale = 1.0f / fmaxf(sqrtf(total), 1e-12f);
  float4 o = { v[0] * scale, v[1] * scale, v[2] * scale, v[3] * scale };
  *(float4*)(outp + (size_t)node * 1024 + base) = o;
}

// ---------------- 256x256 4-phase two-source GEMM (R3 schedule, proven) -----
// C[M,Nc] = [relu](A1@B1t' [+ A2@B2t'] [+ bias]), A bf16 [M,K], Bt bf16 [Nc][K]
// Tile 256x256, BK=64, 8 waves (2M x 4N); quadrant (MH,NH) touches ONLY
// staging half MH of A, NH of B. dbuf 128 KiB. Stage order per iter:
// A-h0, B-h0, B-h1, A-h1; vmcnt(4) at end of phases A, B, D (FIFO-verified).
// PLATEAU NOTE: 8 structural variants (R3-R12) all land at ~5400 cyc/K-tile;
// this is the best measured configuration (884 us @ layer 2, 0 bank conflicts).

template<int K>
__device__ inline void stage_half(char* ldsX, const u16* __restrict__ G, int grow0,
                                  int k0, int h, int wave, int lrow8, int slot8,
                                  int clampR) {
  #pragma unroll
  for (int j = 0; j < 2; ++j) {
    const int lrow = h * 128 + j * 64 + wave * 8;  // wave-uniform
    int gr = grow0 + lrow + lrow8;
    gr = gr < clampR ? gr : clampR - 1;
    gload_lds16(G + (size_t)gr * K + k0 + slot8, ldsX + lrow * 128);
  }
}

#define LOAD_A(MH)                                                              \
  _Pragma("unroll") for (int mf = 0; mf < 4; ++mf) {                            \
    af[mf][0] = *(const bf16x8*)(cA + ((MH) * 128 + mf * 16) * 128 + kc0);      \
    af[mf][1] = *(const bf16x8*)(cA + ((MH) * 128 + mf * 16) * 128 + kc1);      \
  }
#define LOAD_B(DST, NH)                                                         \
  _Pragma("unroll") for (int nf = 0; nf < 2; ++nf) {                            \
    DST[nf][0] = *(const bf16x8*)(cB + ((NH) * 128 + nf * 16) * 128 + kc0);     \
    DST[nf][1] = *(const bf16x8*)(cB + ((NH) * 128 + nf * 16) * 128 + kc1);     \
  }
#define QUAD(MH, BREG, NH)                                                      \
  _Pragma("unroll") for (int mf = 0; mf < 4; ++mf)                              \
  _Pragma("unroll") for (int nf = 0; nf < 2; ++nf) {                            \
    acc[(MH)*4+mf][(NH)*2+nf] = __builtin_amdgcn_mfma_f32_16x16x32_bf16(        \
        af[mf][0], BREG[nf][0], acc[(MH)*4+mf][(NH)*2+nf], 0, 0, 0);            \
    acc[(MH)*4+mf][(NH)*2+nf] = __builtin_amdgcn_mfma_f32_16x16x32_bf16(        \
        af[mf][1], BREG[nf][1], acc[(MH)*4+mf][(NH)*2+nf], 0, 0, 0);            \
  }

template<int K, bool DUAL, bool EPI, bool OUT_F32>
__global__ __launch_bounds__(512, 2)
void gemm2src(const u16* __restrict__ A1, const u16* __restrict__ A2,
              const u16* __restrict__ B1t, const u16* __restrict__ B2t,
              const float* __restrict__ bias, void* __restrict__ Cout,
              int M, int Nc, int tilesN) {
  __shared__ __align__(16) char lds[131072];
  constexpr int NTp = K / 64;
  constexpr int NT = DUAL ? 2 * NTp : NTp;

  // bijective XCD swizzle (gridDim.x % 8 == 0 for all call sites)
  const int nwg = gridDim.x;
  const int bid = blockIdx.x;
  const int wg = (bid & 7) * (nwg >> 3) + (bid >> 3);
  const int bx = wg % tilesN, by = wg / tilesN;
  const int rowBase = by * 256, colBase = bx * 256;

  const int tid = threadIdx.x;
  const int lane = tid & 63;
  const int wave = tid >> 6;
  const int wm = wave >> 2, wn = wave & 3;
  const int r = lane & 15, kg = lane >> 4;
  const int sw = (r & 7) << 4;
  const int kc0 = (kg * 16) ^ sw;
  const int kc1 = (64 + kg * 16) ^ sw;
  const int slot8 = ((lane & 7) ^ ((lane >> 3) & 7)) * 8;  // global chunk, elems
  const int lrow8 = lane >> 3;

  char* const pA0 = lds + (wm * 64 + r) * 128;
  char* const pB0 = lds + 32768 + (wn * 32 + r) * 128;

  f32x4 acc[8][4];
  #pragma unroll
  for (int m = 0; m < 8; ++m)
    #pragma unroll
    for (int n = 0; n < 4; ++n) acc[m][n] = (f32x4){0.f, 0.f, 0.f, 0.f};

  bf16x8 af[4][2], b0[2][2], b1[2][2];

  // prologue: stage tile0 in steady-state order A-h0, B-h0, B-h1, A-h1
  stage_half<K>(lds,         A1,  rowBase, 0, 0, wave, lrow8, slot8, M);
  stage_half<K>(lds + 32768, B1t, colBase, 0, 0, wave, lrow8, slot8, Nc);
  stage_half<K>(lds + 32768, B1t, colBase, 0, 1, wave, lrow8, slot8, Nc);
  stage_half<K>(lds,         A1,  rowBase, 0, 1, wave, lrow8, slot8, M);
  asm volatile("s_waitcnt vmcnt(4)" ::: "memory");  // A-h0 + B-h0 complete
  __builtin_amdgcn_s_barrier();

  for (int t = 0; t < NT; ++t) {
    const int cur = t & 1;
    const char* cA = pA0 + cur * 65536;
    const char* cB = pB0 + cur * 65536;
    char* nA = lds + (cur ^ 1) * 65536;
    char* nB = nA + 32768;
    const int vt = (t + 1 < NT) ? t + 1 : NT - 1;
    const u16* sA; const u16* sB; int sk0;
    if (DUAL && vt >= NTp) { sA = A2; sB = B2t; sk0 = (vt - NTp) * 64; }
    else                   { sA = A1; sB = B1t; sk0 = vt * 64; }

    // ---- phase A: quad (0,0) [A-h0,B-h0]; stage A-h0(t+1); vmcnt(4) ----
    LOAD_A(0); LOAD_B(b0, 0);
    stage_half<K>(nA, sA, rowBase, sk0, 0, wave, lrow8, slot8, M);
    __builtin_amdgcn_s_barrier();
    asm volatile("s_waitcnt lgkmcnt(0)" ::: "memory");
    __builtin_amdgcn_s_setprio(1);
    QUAD(0, b0, 0);
    __builtin_amdgcn_s_setprio(0);
    asm volatile("s_waitcnt vmcnt(4)" ::: "memory");  // B-h1(cur tile) done
    __builtin_amdgcn_s_barrier();

    // ---- phase B: quad (0,1) [A-h0,B-h1]; stage B-h0(t+1); vmcnt(4) ----
    LOAD_B(b1, 1);
    stage_half<K>(nB, sB, colBase, sk0, 0, wave, lrow8, slot8, Nc);
    __builtin_amdgcn_s_barrier();
    asm volatile("s_waitcnt lgkmcnt(0)" ::: "memory");
    __builtin_amdgcn_s_setprio(1);
    QUAD(0, b1, 1);
    __builtin_amdgcn_s_setprio(0);
    asm volatile("s_waitcnt vmcnt(4)" ::: "memory");  // A-h1(cur tile) done
    __builtin_amdgcn_s_barrier();

    // ---- phase C: quad (1,1) [A-h1,B-h1]; stage B-h1(t+1); no vm wait ----
    LOAD_A(1);
    stage_half<K>(nB, sB, colBase, sk0, 1, wave, lrow8, slot8, Nc);
    __builtin_amdgcn_s_barrier();
    asm volatile("s_waitcnt lgkmcnt(0)" ::: "memory");
    __builtin_amdgcn_s_setprio(1);
    QUAD(1, b1, 1);
    __builtin_amdgcn_s_setprio(0);
    __builtin_amdgcn_s_barrier();

    // ---- phase D: quad (1,0) [regs only]; stage A-h1(t+1); vmcnt(4) ----
    stage_half<K>(nA, sA, rowBase, sk0, 1, wave, lrow8, slot8, M);
    __builtin_amdgcn_s_barrier();
    __builtin_amdgcn_s_setprio(1);
    QUAD(1, b0, 0);
    __builtin_amdgcn_s_setprio(0);
    asm volatile("s_waitcnt vmcnt(4)" ::: "memory");  // A-h0+B-h0(next) done
    __builtin_amdgcn_s_barrier();
  }

  // drain stray prefetch before exit
  asm volatile("s_waitcnt vmcnt(0)" ::: "memory");

  // epilogue: [bias + relu] + store (C map: col=lane&15, row=(lane>>4)*4+reg)
  const int q = lane >> 4;
  #pragma unroll
  for (int m = 0; m < 8; ++m) {
    int row = rowBase + (m >> 2) * 128 + wm * 64 + (m & 3) * 16 + q * 4;
    #pragma unroll
    for (int n = 0; n < 4; ++n) {
      int col = colBase + (n >> 1) * 128 + wn * 32 + (n & 1) * 16 + r;
      float bv = EPI ? bias[col] : 0.f;
      #pragma unroll
      for (int reg = 0; reg < 4; ++reg) {
        if (row + reg < M) {
          float v = acc[m][n][reg];
          if constexpr (EPI) v = fmaxf(v + bv, 0.f);
          if constexpr (OUT_F32)
            ((float*)Cout)[(size_t)(row + reg) * Nc + col] = v;
          else
            ((u16*)Cout)[(size_t)(row + reg) * Nc + col] = f2bf(v);
        }
      }
    }
  }
}

// ---------------- launch ----------------
extern "C" void kernel_launch(void* const* d_in, const int* in_sizes, int n_in,
                              void* d_out, int out_size, void* d_ws, size_t ws_size,
                              hipStream_t stream) {
  const float* x   = (const float*)d_in[0];
  const int*   eix = (const int*)d_in[2];
  const float* W1l = (const float*)d_in[3];
  const float* W1r = (const float*)d_in[4];
  const float* b1  = (const float*)d_in[5];
  const float* W2l = (const float*)d_in[6];
  const float* W2r = (const float*)d_in[7];
  const float* b2  = (const float*)d_in[8];
  const float* W3l = (const float*)d_in[9];
  const float* W3r = (const float*)d_in[10];
  const float* b3  = (const float*)d_in[11];

  char* ws = (char*)d_ws;
  size_t off = 0;
  auto alloc = [&](size_t bytes) -> char* {
    char* p = ws + off;
    off += (bytes + 255) & ~(size_t)255;
    return p;
  };
  int* flag   = (int*)alloc(4);
  int* srcA   = (int*)alloc((size_t)EE * 4);
  int* dstA   = (int*)alloc((size_t)EE * 4);
  int* bucket = (int*)alloc((size_t)EE * 4);
  int* cnt    = (int*)alloc((size_t)NN * 4);
  int* offs   = (int*)alloc((size_t)NN * 4);
  int* cursor = (int*)alloc((size_t)NN * 4);
  u16* xb     = (u16*)alloc((size_t)NN * 128 * 2);
  u16* mean1  = (u16*)alloc((size_t)NN * 128 * 2);
  u16* W1lT   = (u16*)alloc((size_t)2048 * 128 * 2);
  u16* W1rT   = (u16*)alloc((size_t)2048 * 128 * 2);
  u16* W2lT   = (u16*)alloc((size_t)2048 * 2048 * 2);
  u16* W2rT   = (u16*)alloc((size_t)2048 * 2048 * 2);
  u16* W3lT   = (u16*)alloc((size_t)1024 * 2048 * 2);  // contiguous with W3rT:
  u16* W3rT   = (u16*)alloc((size_t)1024 * 2048 * 2);  // [W3lT;W3rT] = 2048xK
  u16* bufA   = (u16*)alloc((size_t)NN * 2048 * 2);  // h1, later Y
  u16* bufB   = (u16*)alloc((size_t)NN * 2048 * 2);  // h2
  u16* mean2  = (u16*)d_out;                         // d_out reused as scratch

  // edges -> int32 src/dst
  detect_i64<<<1, 256, 0, stream>>>(eix, flag);
  conv_edges<<<(EE + 255) / 256, 256, 0, stream>>>(eix, flag, srcA, dstA);

  // CSR
  hipMemsetAsync(cnt, 0, (size_t)NN * 4, stream);
  count_edges<<<(EE + 255) / 256, 256, 0, stream>>>(dstA, cnt);
  scan_counts<<<1, 1024, 0, stream>>>(cnt, offs, cursor);
  fill_buckets<<<(EE + 255) / 256, 256, 0, stream>>>(srcA, dstA, cursor, bucket);

  // conversions
  cvt_bf16<<<(NN * 128 / 4 + 255) / 256, 256, 0, stream>>>(x, xb, NN * 128 / 4);
  transposeW<<<dim3(2048 / 32, 128 / 32), dim3(32, 8), 0, stream>>>(W1l, W1lT, 128, 2048);
  transposeW<<<dim3(2048 / 32, 128 / 32), dim3(32, 8), 0, stream>>>(W1r, W1rT, 128, 2048);
  transposeW<<<dim3(2048 / 32, 2048 / 32), dim3(32, 8), 0, stream>>>(W2l, W2lT, 2048, 2048);
  transposeW<<<dim3(2048 / 32, 2048 / 32), dim3(32, 8), 0, stream>>>(W2r, W2rT, 2048, 2048);
  transposeW<<<dim3(1024 / 32, 2048 / 32), dim3(32, 8), 0, stream>>>(W3l, W3lT, 2048, 1024);
  transposeW<<<dim3(1024 / 32, 2048 / 32), dim3(32, 8), 0, stream>>>(W3r, W3rT, 2048, 1024);

  const int tilesM = (NN + 255) / 256;  // 196

  // layer 1: h1 = relu(mean1@W1l + x@W1r + b1)
  agg_mean<128><<<NN, 64, 0, stream>>>(xb, offs, cnt, bucket, mean1);
  gemm2src<128, true, true, false><<<tilesM * 8, 512, 0, stream>>>(
      mean1, xb, W1lT, W1rT, b1, bufA, NN, 2048, 8);

  // layer 2: h2 = relu(mean2@W2l + h1@W2r + b2)
  agg_mean<2048><<<NN, 256, 0, stream>>>(bufA, offs, cnt, bucket, mean2);
  gemm2src<2048, true, true, false><<<tilesM * 8, 512, 0, stream>>>(
      mean2, bufA, W2lT, W2rT, b2, bufB, NN, 2048, 8);

  // layer 3 (restructured): Y = h2@[W3l;W3r] (single-source, no epilogue);
  // then out = l2norm(relu(mean(Y_l) + Y_r + b3))
  gemm2src<2048, false, false, false><<<tilesM * 8, 512, 0, stream>>>(
      bufB, nullptr, W3lT, nullptr, nullptr, bufA, NN, 2048, 8);
  agg_add_norm<<<NN, 256, 0, stream>>>(bufA, offs, cnt, bucket, b3, (float*)d_out);
}

// Round 14
// 1894.591 us; speedup vs baseline: 1.3553x; 1.0447x over previous
//
#include <hip/hip_runtime.h>
#include <stdint.h>

#define NN 50000
#define EE 400000

typedef unsigned short u16;
typedef __attribute__((ext_vector_type(8))) short bf16x8;
typedef __attribute__((ext_vector_type(4))) float f32x4;
typedef __attribute__((address_space(3))) uint32_t lds_u32_t;
typedef __attribute__((address_space(1))) uint32_t glob_u32_t;

__device__ inline float bf2f(u16 u) {
  union { uint32_t i; float f; } x; x.i = ((uint32_t)u) << 16; return x.f;
}
__device__ inline u16 f2bf(float f) {
  union { float f; uint32_t i; } x; x.f = f;
  x.i += 0x7fffu + ((x.i >> 16) & 1u);   // RNE
  return (u16)(x.i >> 16);
}
__device__ inline void gload_lds16(const void* g, void* l) {
  __builtin_amdgcn_global_load_lds((const glob_u32_t*)g, (lds_u32_t*)l, 16, 0, 0);
}

// ---------------- edge dtype detect + normalize ----------------
__global__ void detect_i64(const int* __restrict__ e, int* __restrict__ flag) {
  __shared__ int sh[256];
  int t = threadIdx.x;
  int v = 0;
  for (int i = t; i < 4096; i += 256) v |= e[2 * i + 1];
  sh[t] = v; __syncthreads();
  for (int s = 128; s > 0; s >>= 1) { if (t < s) sh[t] |= sh[t + s]; __syncthreads(); }
  if (t == 0) flag[0] = (sh[0] == 0) ? 1 : 0;   // all high words zero -> int64
}

// fused: edge-dtype normalize + per-dst degree count
__global__ void conv_count(const int* __restrict__ e, const int* __restrict__ flag,
                           int* __restrict__ src, int* __restrict__ dst,
                           int* __restrict__ cnt) {
  int i = blockIdx.x * 256 + threadIdx.x;
  if (i >= EE) return;
  int s, d;
  if (flag[0]) { s = e[2 * i]; d = e[2 * (EE + i)]; }
  else         { s = e[i];     d = e[EE + i]; }
  src[i] = s; dst[i] = d;
  atomicAdd(&cnt[d], 1);
}

// ---------------- bucket-region assignment (replaces prefix scan) -----------
// agg only needs per-node regions contiguous & disjoint, NOT node-ordered.
// One global atomicAdd per node assigns regions fully in parallel (the old
// single-block scan was ~980 serial barriers on one CU). Within-bucket order
// was already nondeterministic (fill_buckets atomics); fp-assoc jitter is
// within the harness tolerance (absmax stable 9.8e-4 across rounds).
__global__ void assign_offs(const int* __restrict__ cnt, int* __restrict__ offs,
                            int* __restrict__ cursor, int* __restrict__ gcur) {
  int i = blockIdx.x * 256 + threadIdx.x;
  if (i >= NN) return;
  int c = cnt[i];
  int b = atomicAdd(gcur, c);
  offs[i] = b; cursor[i] = b;
}

__global__ void fill_buckets(const int* __restrict__ src, const int* __restrict__ dst,
                             int* __restrict__ cursor, int* __restrict__ bucket) {
  int i = blockIdx.x * 256 + threadIdx.x;
  if (i >= EE) return;
  int p = atomicAdd(&cursor[dst[i]], 1);
  bucket[p] = src[i];
}

// ---------------- fp32 -> bf16 conversions ----------------
__global__ void cvt_bf16(const float* __restrict__ in, u16* __restrict__ out, int n4) {
  int i = blockIdx.x * 256 + threadIdx.x;
  if (i >= n4) return;
  float4 v = ((const float4*)in)[i];
  u16 o[4] = { f2bf(v.x), f2bf(v.y), f2bf(v.z), f2bf(v.w) };
  uint2 pack;
  pack.x = (uint32_t)o[0] | ((uint32_t)o[1] << 16);
  pack.y = (uint32_t)o[2] | ((uint32_t)o[3] << 16);
  ((uint2*)out)[i] = pack;
}

// W [K][Nc] fp32 -> Wt [Nc][K] bf16
__global__ void transposeW(const float* __restrict__ W, u16* __restrict__ Wt,
                           int K, int Nc) {
  __shared__ float tile[32][33];
  int n0 = blockIdx.x * 32, k0 = blockIdx.y * 32;
  int tx = threadIdx.x, ty = threadIdx.y;  // 32 x 8
  #pragma unroll
  for (int i = 0; i < 4; ++i)
    tile[ty + i * 8][tx] = W[(size_t)(k0 + ty + i * 8) * Nc + n0 + tx];
  __syncthreads();
  #pragma unroll
  for (int i = 0; i < 4; ++i)
    Wt[(size_t)(n0 + ty + i * 8) * K + k0 + tx] = f2bf(tile[tx][ty + i * 8]);
}

// ---------------- mean aggregation (CSR gather) ----------------
template<int D>
__global__ void agg_mean(const u16* __restrict__ h, const int* __restrict__ offs,
                         const int* __restrict__ cnt, const int* __restrict__ bucket,
                         u16* __restrict__ outp) {
  int node = blockIdx.x;
  int t = threadIdx.x;
  int base = t * 8;
  if (base >= D) return;
  int start = offs[node];
  int c = cnt[node];
  float acc[8];
  #pragma unroll
  for (int i = 0; i < 8; ++i) acc[i] = 0.f;
  for (int j = 0; j < c; ++j) {
    int s = bucket[start + j];
    uint4 q = *(const uint4*)(h + (size_t)s * D + base);
    acc[0] += bf2f((u16)(q.x & 0xffff)); acc[1] += bf2f((u16)(q.x >> 16));
    acc[2] += bf2f((u16)(q.y & 0xffff)); acc[3] += bf2f((u16)(q.y >> 16));
    acc[4] += bf2f((u16)(q.z & 0xffff)); acc[5] += bf2f((u16)(q.z >> 16));
    acc[6] += bf2f((u16)(q.w & 0xffff)); acc[7] += bf2f((u16)(q.w >> 16));
  }
  float inv = 1.0f / fmaxf((float)c, 1.0f);
  uint4 o;
  o.x = (uint32_t)f2bf(acc[0] * inv) | ((uint32_t)f2bf(acc[1] * inv) << 16);
  o.y = (uint32_t)f2bf(acc[2] * inv) | ((uint32_t)f2bf(acc[3] * inv) << 16);
  o.z = (uint32_t)f2bf(acc[4] * inv) | ((uint32_t)f2bf(acc[5] * inv) << 16);
  o.w = (uint32_t)f2bf(acc[6] * inv) | ((uint32_t)f2bf(acc[7] * inv) << 16);
  *(uint4*)(outp + (size_t)node * D + base) = o;
}

// ---- fused layer-3 tail: out = l2norm(relu(mean(Y_l[nbrs]) + Y_r + b3)) ----
// Y [NN][2048] bf16: cols 0..1023 = h2@W3l, cols 1024..2047 = h2@W3r.
__global__ void agg_add_norm(const u16* __restrict__ Y, const int* __restrict__ offs,
                             const int* __restrict__ cnt, const int* __restrict__ bucket,
                             const float* __restrict__ b3, float* __restrict__ outp) {
  int node = blockIdx.x;
  int t = threadIdx.x;
  int base = t * 4;  // 0..1023
  int start = offs[node];
  int c = cnt[node];
  float acc[4] = {0.f, 0.f, 0.f, 0.f};
  for (int j = 0; j < c; ++j) {
    int s = bucket[start + j];
    uint2 q = *(const uint2*)(Y + (size_t)s * 2048 + base);
    acc[0] += bf2f((u16)(q.x & 0xffff)); acc[1] += bf2f((u16)(q.x >> 16));
    acc[2] += bf2f((u16)(q.y & 0xffff)); acc[3] += bf2f((u16)(q.y >> 16));
  }
  float inv = 1.0f / fmaxf((float)c, 1.0f);
  uint2 qr = *(const uint2*)(Y + (size_t)node * 2048 + 1024 + base);
  float yr[4] = { bf2f((u16)(qr.x & 0xffff)), bf2f((u16)(qr.x >> 16)),
                  bf2f((u16)(qr.y & 0xffff)), bf2f((u16)(qr.y >> 16)) };
  float4 bv = *(const float4*)(b3 + base);
  float v[4];
  v[0] = fmaxf(acc[0] * inv + yr[0] + bv.x, 0.f);
  v[1] = fmaxf(acc[1] * inv + yr[1] + bv.y, 0.f);
  v[2] = fmaxf(acc[2] * inv + yr[2] + bv.z, 0.f);
  v[3] = fmaxf(acc[3] * inv + yr[3] + bv.w, 0.f);
  float ss = v[0] * v[0] + v[1] * v[1] + v[2] * v[2] + v[3] * v[3];
  #pragma unroll
  for (int off = 32; off > 0; off >>= 1) ss += __shfl_down(ss, off);
  __shared__ float sw[4];
  int lane = t & 63, w = t >> 6;
  if (lane == 0) sw[w] = ss;
  __syncthreads();
  float total = sw[0] + sw[1] + sw[2] + sw[3];
  float scale = 1.0f / fmaxf(sqrtf(total), 1e-12f);
  float4 o = { v[0] * scale, v[1] * scale, v[2] * scale, v[3] * scale };
  *(float4*)(outp + (size_t)node * 1024 + base) = o;
}

// ---------------- 256x256 4-phase two-source GEMM (R3 schedule, proven) -----
// C[M,Nc] = [relu](A1@B1t' [+ A2@B2t'] [+ bias]), A bf16 [M,K], Bt bf16 [Nc][K]
// Tile 256x256, BK=64, 8 waves (2M x 4N); quadrant (MH,NH) touches ONLY
// staging half MH of A, NH of B. dbuf 128 KiB. Stage order per iter:
// A-h0, B-h0, B-h1, A-h1; vmcnt(4) at end of phases A, B, D (FIFO-verified).
// PLATEAU NOTE: 8 structural variants (R3-R12) all land at ~5400 cyc/K-tile;
// this is the best measured configuration (884 us @ layer 2, 0 bank conflicts).

template<int K>
__device__ inline void stage_half(char* ldsX, const u16* __restrict__ G, int grow0,
                                  int k0, int h, int wave, int lrow8, int slot8,
                                  int clampR) {
  #pragma unroll
  for (int j = 0; j < 2; ++j) {
    const int lrow = h * 128 + j * 64 + wave * 8;  // wave-uniform
    int gr = grow0 + lrow + lrow8;
    gr = gr < clampR ? gr : clampR - 1;
    gload_lds16(G + (size_t)gr * K + k0 + slot8, ldsX + lrow * 128);
  }
}

#define LOAD_A(MH)                                                              \
  _Pragma("unroll") for (int mf = 0; mf < 4; ++mf) {                            \
    af[mf][0] = *(const bf16x8*)(cA + ((MH) * 128 + mf * 16) * 128 + kc0);      \
    af[mf][1] = *(const bf16x8*)(cA + ((MH) * 128 + mf * 16) * 128 + kc1);      \
  }
#define LOAD_B(DST, NH)                                                         \
  _Pragma("unroll") for (int nf = 0; nf < 2; ++nf) {                            \
    DST[nf][0] = *(const bf16x8*)(cB + ((NH) * 128 + nf * 16) * 128 + kc0);     \
    DST[nf][1] = *(const bf16x8*)(cB + ((NH) * 128 + nf * 16) * 128 + kc1);     \
  }
#define QUAD(MH, BREG, NH)                                                      \
  _Pragma("unroll") for (int mf = 0; mf < 4; ++mf)                              \
  _Pragma("unroll") for (int nf = 0; nf < 2; ++nf) {                            \
    acc[(MH)*4+mf][(NH)*2+nf] = __builtin_amdgcn_mfma_f32_16x16x32_bf16(        \
        af[mf][0], BREG[nf][0], acc[(MH)*4+mf][(NH)*2+nf], 0, 0, 0);            \
    acc[(MH)*4+mf][(NH)*2+nf] = __builtin_amdgcn_mfma_f32_16x16x32_bf16(        \
        af[mf][1], BREG[nf][1], acc[(MH)*4+mf][(NH)*2+nf], 0, 0, 0);            \
  }

template<int K, bool DUAL, bool EPI, bool OUT_F32>
__global__ __launch_bounds__(512, 2)
void gemm2src(const u16* __restrict__ A1, const u16* __restrict__ A2,
              const u16* __restrict__ B1t, const u16* __restrict__ B2t,
              const float* __restrict__ bias, void* __restrict__ Cout,
              int M, int Nc, int tilesN) {
  __shared__ __align__(16) char lds[131072];
  constexpr int NTp = K / 64;
  constexpr int NT = DUAL ? 2 * NTp : NTp;

  // bijective XCD swizzle (gridDim.x % 8 == 0 for all call sites)
  const int nwg = gridDim.x;
  const int bid = blockIdx.x;
  const int wg = (bid & 7) * (nwg >> 3) + (bid >> 3);
  const int bx = wg % tilesN, by = wg / tilesN;
  const int rowBase = by * 256, colBase = bx * 256;

  const int tid = threadIdx.x;
  const int lane = tid & 63;
  const int wave = tid >> 6;
  const int wm = wave >> 2, wn = wave & 3;
  const int r = lane & 15, kg = lane >> 4;
  const int sw = (r & 7) << 4;
  const int kc0 = (kg * 16) ^ sw;
  const int kc1 = (64 + kg * 16) ^ sw;
  const int slot8 = ((lane & 7) ^ ((lane >> 3) & 7)) * 8;  // global chunk, elems
  const int lrow8 = lane >> 3;

  char* const pA0 = lds + (wm * 64 + r) * 128;
  char* const pB0 = lds + 32768 + (wn * 32 + r) * 128;

  f32x4 acc[8][4];
  #pragma unroll
  for (int m = 0; m < 8; ++m)
    #pragma unroll
    for (int n = 0; n < 4; ++n) acc[m][n] = (f32x4){0.f, 0.f, 0.f, 0.f};

  bf16x8 af[4][2], b0[2][2], b1[2][2];

  // prologue: stage tile0 in steady-state order A-h0, B-h0, B-h1, A-h1
  stage_half<K>(lds,         A1,  rowBase, 0, 0, wave, lrow8, slot8, M);
  stage_half<K>(lds + 32768, B1t, colBase, 0, 0, wave, lrow8, slot8, Nc);
  stage_half<K>(lds + 32768, B1t, colBase, 0, 1, wave, lrow8, slot8, Nc);
  stage_half<K>(lds,         A1,  rowBase, 0, 1, wave, lrow8, slot8, M);
  asm volatile("s_waitcnt vmcnt(4)" ::: "memory");  // A-h0 + B-h0 complete
  __builtin_amdgcn_s_barrier();

  for (int t = 0; t < NT; ++t) {
    const int cur = t & 1;
    const char* cA = pA0 + cur * 65536;
    const char* cB = pB0 + cur * 65536;
    char* nA = lds + (cur ^ 1) * 65536;
    char* nB = nA + 32768;
    const int vt = (t + 1 < NT) ? t + 1 : NT - 1;
    const u16* sA; const u16* sB; int sk0;
    if (DUAL && vt >= NTp) { sA = A2; sB = B2t; sk0 = (vt - NTp) * 64; }
    else                   { sA = A1; sB = B1t; sk0 = vt * 64; }

    // ---- phase A: quad (0,0) [A-h0,B-h0]; stage A-h0(t+1); vmcnt(4) ----
    LOAD_A(0); LOAD_B(b0, 0);
    stage_half<K>(nA, sA, rowBase, sk0, 0, wave, lrow8, slot8, M);
    __builtin_amdgcn_s_barrier();
    asm volatile("s_waitcnt lgkmcnt(0)" ::: "memory");
    __builtin_amdgcn_s_setprio(1);
    QUAD(0, b0, 0);
    __builtin_amdgcn_s_setprio(0);
    asm volatile("s_waitcnt vmcnt(4)" ::: "memory");  // B-h1(cur tile) done
    __builtin_amdgcn_s_barrier();

    // ---- phase B: quad (0,1) [A-h0,B-h1]; stage B-h0(t+1); vmcnt(4) ----
    LOAD_B(b1, 1);
    stage_half<K>(nB, sB, colBase, sk0, 0, wave, lrow8, slot8, Nc);
    __builtin_amdgcn_s_barrier();
    asm volatile("s_waitcnt lgkmcnt(0)" ::: "memory");
    __builtin_amdgcn_s_setprio(1);
    QUAD(0, b1, 1);
    __builtin_amdgcn_s_setprio(0);
    asm volatile("s_waitcnt vmcnt(4)" ::: "memory");  // A-h1(cur tile) done
    __builtin_amdgcn_s_barrier();

    // ---- phase C: quad (1,1) [A-h1,B-h1]; stage B-h1(t+1); no vm wait ----
    LOAD_A(1);
    stage_half<K>(nB, sB, colBase, sk0, 1, wave, lrow8, slot8, Nc);
    __builtin_amdgcn_s_barrier();
    asm volatile("s_waitcnt lgkmcnt(0)" ::: "memory");
    __builtin_amdgcn_s_setprio(1);
    QUAD(1, b1, 1);
    __builtin_amdgcn_s_setprio(0);
    __builtin_amdgcn_s_barrier();

    // ---- phase D: quad (1,0) [regs only]; stage A-h1(t+1); vmcnt(4) ----
    stage_half<K>(nA, sA, rowBase, sk0, 1, wave, lrow8, slot8, M);
    __builtin_amdgcn_s_barrier();
    __builtin_amdgcn_s_setprio(1);
    QUAD(1, b0, 0);
    __builtin_amdgcn_s_setprio(0);
    asm volatile("s_waitcnt vmcnt(4)" ::: "memory");  // A-h0+B-h0(next) done
    __builtin_amdgcn_s_barrier();
  }

  // drain stray prefetch before exit
  asm volatile("s_waitcnt vmcnt(0)" ::: "memory");

  // epilogue: [bias + relu] + store (C map: col=lane&15, row=(lane>>4)*4+reg)
  const int q = lane >> 4;
  #pragma unroll
  for (int m = 0; m < 8; ++m) {
    int row = rowBase + (m >> 2) * 128 + wm * 64 + (m & 3) * 16 + q * 4;
    #pragma unroll
    for (int n = 0; n < 4; ++n) {
      int col = colBase + (n >> 1) * 128 + wn * 32 + (n & 1) * 16 + r;
      float bv = EPI ? bias[col] : 0.f;
      #pragma unroll
      for (int reg = 0; reg < 4; ++reg) {
        if (row + reg < M) {
          float v = acc[m][n][reg];
          if constexpr (EPI) v = fmaxf(v + bv, 0.f);
          if constexpr (OUT_F32)
            ((float*)Cout)[(size_t)(row + reg) * Nc + col] = v;
          else
            ((u16*)Cout)[(size_t)(row + reg) * Nc + col] = f2bf(v);
        }
      }
    }
  }
}

// ---------------- launch ----------------
extern "C" void kernel_launch(void* const* d_in, const int* in_sizes, int n_in,
                              void* d_out, int out_size, void* d_ws, size_t ws_size,
                              hipStream_t stream) {
  const float* x   = (const float*)d_in[0];
  const int*   eix = (const int*)d_in[2];
  const float* W1l = (const float*)d_in[3];
  const float* W1r = (const float*)d_in[4];
  const float* b1  = (const float*)d_in[5];
  const float* W2l = (const float*)d_in[6];
  const float* W2r = (const float*)d_in[7];
  const float* b2  = (const float*)d_in[8];
  const float* W3l = (const float*)d_in[9];
  const float* W3r = (const float*)d_in[10];
  const float* b3  = (const float*)d_in[11];

  char* ws = (char*)d_ws;
  size_t off = 0;
  auto alloc = [&](size_t bytes) -> char* {
    char* p = ws + off;
    off += (bytes + 255) & ~(size_t)255;
    return p;
  };
  int* flag   = (int*)alloc(4);
  int* gcur   = (int*)alloc(4);
  int* srcA   = (int*)alloc((size_t)EE * 4);
  int* dstA   = (int*)alloc((size_t)EE * 4);
  int* bucket = (int*)alloc((size_t)EE * 4);
  int* cnt    = (int*)alloc((size_t)NN * 4);
  int* offs   = (int*)alloc((size_t)NN * 4);
  int* cursor = (int*)alloc((size_t)NN * 4);
  u16* xb     = (u16*)alloc((size_t)NN * 128 * 2);
  u16* mean1  = (u16*)alloc((size_t)NN * 128 * 2);
  u16* W1lT   = (u16*)alloc((size_t)2048 * 128 * 2);
  u16* W1rT   = (u16*)alloc((size_t)2048 * 128 * 2);
  u16* W2lT   = (u16*)alloc((size_t)2048 * 2048 * 2);
  u16* W2rT   = (u16*)alloc((size_t)2048 * 2048 * 2);
  u16* W3lT   = (u16*)alloc((size_t)1024 * 2048 * 2);  // contiguous with W3rT:
  u16* W3rT   = (u16*)alloc((size_t)1024 * 2048 * 2);  // [W3lT;W3rT] = 2048xK
  u16* bufA   = (u16*)alloc((size_t)NN * 2048 * 2);  // h1, later Y
  u16* bufB   = (u16*)alloc((size_t)NN * 2048 * 2);  // h2
  u16* mean2  = (u16*)d_out;                         // d_out reused as scratch

  // edges -> int32 src/dst (+degree count), parallel region assignment
  detect_i64<<<1, 256, 0, stream>>>(eix, flag);
  hipMemsetAsync(cnt, 0, (size_t)NN * 4, stream);
  hipMemsetAsync(gcur, 0, 4, stream);
  conv_count<<<(EE + 255) / 256, 256, 0, stream>>>(eix, flag, srcA, dstA, cnt);
  assign_offs<<<(NN + 255) / 256, 256, 0, stream>>>(cnt, offs, cursor, gcur);
  fill_buckets<<<(EE + 255) / 256, 256, 0, stream>>>(srcA, dstA, cursor, bucket);

  // conversions
  cvt_bf16<<<(NN * 128 / 4 + 255) / 256, 256, 0, stream>>>(x, xb, NN * 128 / 4);
  transposeW<<<dim3(2048 / 32, 128 / 32), dim3(32, 8), 0, stream>>>(W1l, W1lT, 128, 2048);
  transposeW<<<dim3(2048 / 32, 128 / 32), dim3(32, 8), 0, stream>>>(W1r, W1rT, 128, 2048);
  transposeW<<<dim3(2048 / 32, 2048 / 32), dim3(32, 8), 0, stream>>>(W2l, W2lT, 2048, 2048);
  transposeW<<<dim3(2048 / 32, 2048 / 32), dim3(32, 8), 0, stream>>>(W2r, W2rT, 2048, 2048);
  transposeW<<<dim3(1024 / 32, 2048 / 32), dim3(32, 8), 0, stream>>>(W3l, W3lT, 2048, 1024);
  transposeW<<<dim3(1024 / 32, 2048 / 32), dim3(32, 8), 0, stream>>>(W3r, W3rT, 2048, 1024);

  const int tilesM = (NN + 255) / 256;  // 196

  // layer 1: h1 = relu(mean1@W1l + x@W1r + b1)
  agg_mean<128><<<NN, 64, 0, stream>>>(xb, offs, cnt, bucket, mean1);
  gemm2src<128, true, true, false><<<tilesM * 8, 512, 0, stream>>>(
      mean1, xb, W1lT, W1rT, b1, bufA, NN, 2048, 8);

  // layer 2: h2 = relu(mean2@W2l + h1@W2r + b2)
  agg_mean<2048><<<NN, 256, 0, stream>>>(bufA, offs, cnt, bucket, mean2);
  gemm2src<2048, true, true, false><<<tilesM * 8, 512, 0, stream>>>(
      mean2, bufA, W2lT, W2rT, b2, bufB, NN, 2048, 8);

  // layer 3 (restructured): Y = h2@[W3l;W3r] (single-source, no epilogue);
  // then out = l2norm(relu(mean(Y_l) + Y_r + b3))
  gemm2src<2048, false, false, false><<<tilesM * 8, 512, 0, stream>>>(
      bufB, nullptr, W3lT, nullptr, nullptr, bufA, NN, 2048, 8);
  agg_add_norm<<<NN, 256, 0, stream>>>(bufA, offs, cnt, bucket, b3, (float*)d_out);
}